// Round 1
// baseline (486.658 us; speedup 1.0000x reference)
//
#include <hip/hip_runtime.h>
#include <hip/hip_fp16.h>

#define TT 512
#define NDIAG 1023              // diagonals kd = ii+jj in [0, 1022]
#define TOTCELL 262144          // TT*TT packed cells per sample
#define BIGS 1.4426950408889634e10f   // BIG(1e10) * log2(e), scaled domain
#define LOG2E 1.4426950408889634f
#define LN2F 0.69314718055994531f

// packed offset of diagonal kd = number of cells on diagonals < kd
__device__ __forceinline__ int diag_off(int kd) {
    return (kd <= 512) ? (kd * (kd + 1)) / 2
                       : TOTCELL - ((1023 - kd) * (1024 - kd)) / 2;
}

// ---------------------------------------------------------------------------
// Kernel 1: D'[n][kd][pos] = |X[n,i]-Z[j]|^2 * log2(e), packed anti-diagonal
// layout, fp16. Tiles 64x64 in (i,j) space; 256 threads, 4x4 micro-tile per
// thread; X/Z tiles staged transposed in LDS so the c-loop reads float4.
// Scattered 2B stores into diag layout; every line fully covered -> L2 merges.
// ---------------------------------------------------------------------------
__global__ __launch_bounds__(256) void k_dist(const float* __restrict__ X,
                                              const float* __restrict__ Z,
                                              __half* __restrict__ Dd) {
    const int n  = blockIdx.x;
    const int i0 = blockIdx.y * 64;
    const int j0 = blockIdx.z * 64;
    __shared__ float Xt[16][64];   // Xt[c][i_local]
    __shared__ float Zt[16][64];   // Zt[c][j_local]
    const int t = threadIdx.x;
    {
        const int r  = t >> 2;          // 0..63 row of the tile
        const int cq = (t & 3) * 4;     // 0,4,8,12 dim quad
        const float4 gx = *(const float4*)&X[((size_t)n * TT + (i0 + r)) * 16 + cq];
        Xt[cq + 0][r] = gx.x; Xt[cq + 1][r] = gx.y;
        Xt[cq + 2][r] = gx.z; Xt[cq + 3][r] = gx.w;
        const float4 gz = *(const float4*)&Z[(size_t)(j0 + r) * 16 + cq];
        Zt[cq + 0][r] = gz.x; Zt[cq + 1][r] = gz.y;
        Zt[cq + 2][r] = gz.z; Zt[cq + 3][r] = gz.w;
    }
    __syncthreads();

    const int iq = (t & 15) * 4;    // 16 i-quads
    const int jq = (t >> 4) * 4;    // 16 j-quads
    float acc[4][4] = {};
#pragma unroll
    for (int c = 0; c < 16; ++c) {
        const float4 xa = *(const float4*)&Xt[c][iq];
        const float4 zb = *(const float4*)&Zt[c][jq];
        const float xs[4] = {xa.x, xa.y, xa.z, xa.w};
        const float zs[4] = {zb.x, zb.y, zb.z, zb.w};
#pragma unroll
        for (int u = 0; u < 4; ++u)
#pragma unroll
            for (int v = 0; v < 4; ++v) {
                const float d = xs[u] - zs[v];
                acc[u][v] = fmaf(d, d, acc[u][v]);
            }
    }

    __half* base = Dd + (size_t)n * TOTCELL;
#pragma unroll
    for (int u = 0; u < 4; ++u) {
        const int ii = i0 + iq + u;
#pragma unroll
        for (int v = 0; v < 4; ++v) {
            const int jj = j0 + jq + v;
            const int kd = ii + jj;
            const int start = (kd > 511) ? (kd - 511) : 0;
            const int idx = diag_off(kd) + (ii - start);
            base[idx] = __float2half(acc[u][v] * LOG2E);
        }
    }
}

// ---------------------------------------------------------------------------
// Kernel 2: SoftDTW DP, one block per sample, thread = row ii. One barrier
// per diagonal; wave-boundary values through parity-double-buffered LDS;
// next diagonal's D prefetched (register load stays in flight across barrier).
// Everything in the base-2 scaled domain (values = true * log2(e)).
// ---------------------------------------------------------------------------
__global__ __launch_bounds__(512) void k_dp(const __half* __restrict__ Dd,
                                            const float* __restrict__ w,
                                            float* __restrict__ out) {
    const int n    = blockIdx.x;
    const int ii   = threadIdx.x;
    const int lane = ii & 63;
    const int wv   = ii >> 6;       // wave index 0..7
    __shared__ float b1[2][8];      // [parity][wave] lane-63 prev1
    __shared__ float b2[2][8];      // [parity][wave] lane-63 prev2
    if (ii < 8) { b1[1][ii] = BIGS; b2[1][ii] = BIGS; }

    const __half* base = Dd + (size_t)n * TOTCELL;
    float p1 = BIGS, p2 = BIGS;     // prev1 (kd-1), prev2 (kd-2) for this row
    float dcur = __half2float(base[0]);  // kd=0: only ii==0 valid; clamp->cell 0
    __syncthreads();

    for (int kd = 0; kd < NDIAG; ++kd) {
        // ---- prefetch D for kd+1 (clamped into the packed row; garbage for
        //      invalid lanes is fine, it gets masked) ----
        float dnext = 0.0f;
        const int kn = kd + 1;
        if (kn < NDIAG) {
            const int st = (kn > 511) ? (kn - 511) : 0;
            const int ln = (kn < 512) ? (kn + 1) : (1023 - kn);
            int pos = ii - st;
            pos = pos < 0 ? 0 : pos;
            pos = pos > ln - 1 ? ln - 1 : pos;
            dnext = __half2float(base[diag_off(kn) + pos]);
        }

        // ---- neighbor (row ii-1) values of prev1/prev2 ----
        float u1 = __shfl_up(p1, 1);      // R[i-1, j]   (diag kd-1)
        float u2 = __shfl_up(p2, 1);      // R[i-1, j-1] (diag kd-2)
        const int slotR = (kd + 1) & 1;   // slot written at iteration kd-1
        if (lane == 0) {
            if (wv == 0) { u1 = BIGS; u2 = (kd == 0) ? 0.0f : BIGS; }
            else         { u1 = b1[slotR][wv - 1]; u2 = b2[slotR][wv - 1]; }
        }

        const int jj = kd - ii;
        const bool valid = (jj >= 0) && (jj < TT);

        // softmin in base-2: r = D' + m - log2(2^(m-a)+2^(m-b)+2^(m-c))
        const float m = fminf(fminf(u1, p1), u2);
        const float s = exp2f(m - u1) + exp2f(m - p1) + exp2f(m - u2);
        const float r = dcur + (m - log2f(s));
        const float rnew = valid ? r : BIGS;

        if (lane == 63) { b1[kd & 1][wv] = rnew; b2[kd & 1][wv] = p1; }
        __syncthreads();

        p2 = p1; p1 = rnew; dcur = dnext;
    }

    // thread 511 holds R[T,T] (scaled); unscale by ln2 and accumulate
    if (ii == TT - 1) {
        atomicAdd(out, w[n] * p1 * LN2F);
    }
}

__global__ void k_zero(float* out) {
    if (threadIdx.x == 0 && blockIdx.x == 0) out[0] = 0.0f;
}

extern "C" void kernel_launch(void* const* d_in, const int* in_sizes, int n_in,
                              void* d_out, int out_size, void* d_ws, size_t ws_size,
                              hipStream_t stream) {
    const float* X = (const float*)d_in[0];   // (64, 512, 16) f32
    const float* w = (const float*)d_in[1];   // (64,) f32
    const float* Z = (const float*)d_in[2];   // (512, 16) f32
    float* out = (float*)d_out;               // scalar f32
    __half* Dd = (__half*)d_ws;               // 64 * 262144 * 2 B = 32 MiB

    hipLaunchKernelGGL(k_zero, dim3(1), dim3(64), 0, stream, out);
    hipLaunchKernelGGL(k_dist, dim3(64, 8, 8), dim3(256), 0, stream, X, Z, Dd);
    hipLaunchKernelGGL(k_dp, dim3(64), dim3(512), 0, stream, Dd, w, out);
}